// Round 1
// baseline (1331.948 us; speedup 1.0000x reference)
//
#include <hip/hip_runtime.h>
#include <math.h>

#define D   256
#define SE  512
#define SC  512
#define CKS 8
#define NC  64   // SC / CKS
#define KC  3

__device__ __forceinline__ float sigmoidf_(float x) { return 1.f / (1.f + __expf(-x)); }

// ---------- emo/cau = relu(text @ rep_W + rep_b), rows 0..511 = emo, 512..1023 = cau ----------
__global__ __launch_bounds__(256) void rep_kernel(
    const float* __restrict__ te, const float* __restrict__ tc,
    const float* __restrict__ W,  const float* __restrict__ b,
    float* __restrict__ emo, float* __restrict__ cau)
{
    const int row = blockIdx.x;
    const float* x; float* o;
    if (row < SE) { x = te + row * D;        o = emo + row * D; }
    else          { x = tc + (row - SE) * D; o = cau + (row - SE) * D; }
    __shared__ float xs[D];
    const int k = threadIdx.x;
    xs[k] = x[k];
    __syncthreads();
    float acc = b[k];
    #pragma unroll 8
    for (int d = 0; d < D; ++d) acc = fmaf(xs[d], W[d * D + k], acc);
    o[k] = fmaxf(acc, 0.f);
}

// ---------- GRU over each chunk of 8 cau rows; one block (768 thr) per chunk ----------
__global__ __launch_bounds__(768) void gru_kernel(
    const float* __restrict__ cau,
    const float* __restrict__ Wih, const float* __restrict__ Whh,
    const float* __restrict__ bih, const float* __restrict__ bhh,
    float* __restrict__ ch_last)
{
    const int c = blockIdx.x;
    const int t = threadIdx.x;           // 0..767
    __shared__ float h[D], x[D], gx[3 * D], gh[3 * D];
    if (t < D) h[t] = 0.f;
    __syncthreads();
    for (int s = 0; s < CKS; ++s) {
        if (t < D) x[t] = cau[(c * CKS + s) * D + t];
        __syncthreads();
        float a = bih[t], g = bhh[t];
        #pragma unroll 4
        for (int d = 0; d < D; ++d) {
            a = fmaf(x[d], Wih[d * 768 + t], a);
            g = fmaf(h[d], Whh[d * 768 + t], g);
        }
        gx[t] = a; gh[t] = g;
        __syncthreads();
        if (t < D) {
            float r = sigmoidf_(gx[t] + gh[t]);
            float z = sigmoidf_(gx[D + t] + gh[D + t]);
            float n = tanhf(gx[2 * D + t] + r * gh[2 * D + t]);
            h[t] = (1.f - z) * n + z * h[t];
        }
        __syncthreads();
    }
    if (t < D) ch_last[c * D + t] = h[t];
}

// ---------- dual linear: O1 = X1 @ W[0:D], O2 = X2 @ W[D:2D] + bias ----------
__global__ __launch_bounds__(256) void dual_lin_kernel(
    const float* __restrict__ X1, int n1,
    const float* __restrict__ X2,
    const float* __restrict__ W,    // (2D, D) row-major slice of the weight
    const float* __restrict__ bias, // folded into O2 only
    float* __restrict__ O1, float* __restrict__ O2)
{
    const int row = blockIdx.x;
    const int k = threadIdx.x;
    const float* x; const float* Wp; float* o; float acc;
    if (row < n1) { x = X1 + row * D;        Wp = W;         o = O1 + row * D;        acc = 0.f; }
    else          { x = X2 + (row - n1) * D; Wp = W + D * D; o = O2 + (row - n1) * D; acc = bias[k]; }
    __shared__ float xs[D];
    xs[k] = x[k];
    __syncthreads();
    #pragma unroll 8
    for (int d = 0; d < D; ++d) acc = fmaf(xs[d], Wp[d * D + k], acc);
    o[k] = acc;
}

// ---------- phase2: log_softmax(sigmoid(HE[i]+HC[c]) @ Wo + Wob) ----------
__global__ __launch_bounds__(256) void phase2_kernel(
    const float* __restrict__ HE, const float* __restrict__ HC,
    const float* __restrict__ WoW, const float* __restrict__ Wob,
    float* __restrict__ out)
{
    const int i = blockIdx.x, c = blockIdx.y;
    const int k = threadIdx.x;
    const int lane = k & 63, wid = k >> 6;
    float hk = sigmoidf_(HE[i * D + k] + HC[c * D + k]);   // W_b folded into HC
    float v0 = hk * WoW[k * 2 + 0];
    float v1 = hk * WoW[k * 2 + 1];
    #pragma unroll
    for (int off = 32; off; off >>= 1) { v0 += __shfl_down(v0, off); v1 += __shfl_down(v1, off); }
    __shared__ float r0[4], r1[4];
    if (lane == 0) { r0[wid] = v0; r1[wid] = v1; }
    __syncthreads();
    if (k == 0) {
        float l0 = r0[0] + r0[1] + r0[2] + r0[3] + Wob[0];
        float l1 = r1[0] + r1[1] + r1[2] + r1[3] + Wob[1];
        float m = fmaxf(l0, l1);
        float lse = m + __logf(__expf(l0 - m) + __expf(l1 - m));
        out[(i * NC + c) * 2 + 0] = l0 - lse;
        out[(i * NC + c) * 2 + 1] = l1 - lse;
    }
}

// ---------- p: per (i, 64-j tile): M-term + epilogue (relu -> cls -> log_softmax) ----------
// M[i,j,k] = sum_d emo[i,d]*cau[j,d]*W3[513+d,k]; s = M + Ae[i,k] + Ac[j,k](+b) + item2*W3[512,k]
__global__ __launch_bounds__(256) void p_kernel(
    const float* __restrict__ emo, const float* __restrict__ cau,
    const float* __restrict__ Ae,  const float* __restrict__ Ac,
    const float* __restrict__ W3,   // full (769, 256)
    const float* __restrict__ clsW, const float* __restrict__ clsb,
    float* __restrict__ pout)
{
    const int i  = blockIdx.x;
    const int j0 = blockIdx.y * 64;
    const int k  = threadIdx.x;
    const int lane = k & 63, wid = k >> 6;

    __shared__ __align__(16) float e[D];
    __shared__ __align__(16) float ct[64][D + 4];   // stride 260: breaks item2-pass conflicts
    __shared__ float it2[64];
    __shared__ float part[64][4][2];

    e[k] = emo[i * D + k];
    #pragma unroll
    for (int j = 0; j < 64; ++j) ct[j][k] = cau[(j0 + j) * D + k];
    __syncthreads();

    // item2: 4 threads per j
    {
        const int j = k >> 2, dd = k & 3;
        float s = 0.f;
        for (int d = dd; d < D; d += 4) { float df = e[d] - ct[j][d]; s = fmaf(df, df, s); }
        s += __shfl_xor(s, 1);
        s += __shfl_xor(s, 2);
        if (dd == 0) it2[j] = sqrtf(s);
    }
    __syncthreads();

    const float* W3n = W3 + 513 * D;
    float acc[64];
    #pragma unroll
    for (int j = 0; j < 64; ++j) acc[j] = 0.f;

    for (int d4 = 0; d4 < D; d4 += 4) {
        const float4 e4 = *(const float4*)&e[d4];
        const float w0 = W3n[(d4 + 0) * D + k];
        const float w1 = W3n[(d4 + 1) * D + k];
        const float w2 = W3n[(d4 + 2) * D + k];
        const float w3 = W3n[(d4 + 3) * D + k];
        const float q0 = e4.x * w0, q1 = e4.y * w1, q2 = e4.z * w2, q3 = e4.w * w3;
        #pragma unroll
        for (int j = 0; j < 64; ++j) {
            const float4 c4 = *(const float4*)&ct[j][d4];
            float a = acc[j];
            a = fmaf(q0, c4.x, a);
            a = fmaf(q1, c4.y, a);
            a = fmaf(q2, c4.z, a);
            a = fmaf(q3, c4.w, a);
            acc[j] = a;
        }
    }

    const float aek = Ae[i * D + k];
    const float wnk = W3[512 * D + k];
    const float c0 = clsW[k * 2 + 0], c1 = clsW[k * 2 + 1];
    #pragma unroll
    for (int j = 0; j < 64; ++j) {
        float s = acc[j] + aek + Ac[(j0 + j) * D + k] + it2[j] * wnk;  // W3_b folded into Ac
        float h = fmaxf(s, 0.f);
        float v0 = h * c0, v1 = h * c1;
        #pragma unroll
        for (int off = 32; off; off >>= 1) { v0 += __shfl_down(v0, off); v1 += __shfl_down(v1, off); }
        if (lane == 0) { part[j][wid][0] = v0; part[j][wid][1] = v1; }
    }
    __syncthreads();
    if (k < 64) {
        const int j = k;
        float l0 = part[j][0][0] + part[j][1][0] + part[j][2][0] + part[j][3][0] + clsb[0];
        float l1 = part[j][0][1] + part[j][1][1] + part[j][2][1] + part[j][3][1] + clsb[1];
        float m = fmaxf(l0, l1);
        float lse = m + __logf(__expf(l0 - m) + __expf(l1 - m));
        pout[(i * SC + j0 + j) * 2 + 0] = l0 - lse;
        pout[(i * SC + j0 + j) * 2 + 1] = l1 - lse;
    }
}

// ---------- L_cau ----------
__global__ void zero_kernel(float* __restrict__ p, int n)
{
    int i = blockIdx.x * blockDim.x + threadIdx.x;
    if (i < n) p[i] = 0.f;
}
__global__ void scatter_kernel(const int* __restrict__ label3, float* __restrict__ Lcau)
{
    int i = blockIdx.x * blockDim.x + threadIdx.x;
    if (i < SE) {
        #pragma unroll
        for (int t = 0; t < KC; ++t) {
            int j = label3[i * KC + t];
            Lcau[i * SC + j] = 1.0f;
        }
    }
}

extern "C" void kernel_launch(void* const* d_in, const int* in_sizes, int n_in,
                              void* d_out, int out_size, void* d_ws, size_t ws_size,
                              hipStream_t stream)
{
    const float* text_emo = (const float*)d_in[0];
    const float* text_cau = (const float*)d_in[1];
    /* d_in[2] label_ck: unused by the reference output */
    const int*   label3   = (const int*)d_in[3];
    /* d_in[4] chunksize == 8 (compile-time CKS) */
    const float* rep_W = (const float*)d_in[5];
    const float* rep_b = (const float*)d_in[6];
    const float* W_W   = (const float*)d_in[7];
    const float* W_b   = (const float*)d_in[8];
    const float* Wo_W  = (const float*)d_in[9];
    const float* Wo_b  = (const float*)d_in[10];
    const float* gWih  = (const float*)d_in[11];
    const float* gWhh  = (const float*)d_in[12];
    const float* gbih  = (const float*)d_in[13];
    const float* gbhh  = (const float*)d_in[14];
    const float* W3_W  = (const float*)d_in[15];
    const float* W3_b  = (const float*)d_in[16];
    const float* cls_W = (const float*)d_in[17];
    const float* cls_b = (const float*)d_in[18];

    float* out        = (float*)d_out;
    float* phase2_out = out;                       // 512*64*2 = 65536
    float* p_out      = out + SE * NC * 2;         // 512*512*2 = 524288
    float* lcau_out   = out + SE * NC * 2 + SE * SC * 2;

    // workspace (f32): total 688128 floats = 2.75 MB
    float* ws  = (float*)d_ws;
    float* emo = ws;              // 512*256
    float* cau = emo + SE * D;    // 512*256
    float* chl = cau + SC * D;    // 64*256
    float* HE  = chl + NC * D;    // 512*256
    float* HC  = HE + SE * D;     // 64*256
    float* Ae  = HC + NC * D;     // 512*256
    float* Ac  = Ae + SE * D;     // 512*256

    rep_kernel<<<SE + SC, 256, 0, stream>>>(text_emo, text_cau, rep_W, rep_b, emo, cau);
    gru_kernel<<<NC, 768, 0, stream>>>(cau, gWih, gWhh, gbih, gbhh, chl);
    dual_lin_kernel<<<SE + NC, 256, 0, stream>>>(emo, SE, chl, W_W, W_b, HE, HC);
    dual_lin_kernel<<<SE + SC, 256, 0, stream>>>(emo, SE, cau, W3_W, W3_b, Ae, Ac);
    phase2_kernel<<<dim3(SE, NC), 256, 0, stream>>>(HE, HC, Wo_W, Wo_b, phase2_out);
    p_kernel<<<dim3(SE, 8), 256, 0, stream>>>(emo, cau, Ae, Ac, W3_W, cls_W, cls_b, p_out);
    zero_kernel<<<(SE * SC + 255) / 256, 256, 0, stream>>>(lcau_out, SE * SC);
    scatter_kernel<<<2, 256, 0, stream>>>(label3, lcau_out);
}

// Round 2
// 304.395 us; speedup vs baseline: 4.3757x; 4.3757x over previous
//
#include <hip/hip_runtime.h>
#include <hip/hip_bf16.h>
#include <math.h>

#define D   256
#define SE  512
#define SC  512
#define CKS 8
#define NC  64   // SC / CKS
#define KC  3

typedef __attribute__((ext_vector_type(8))) short short8_t;
typedef __attribute__((ext_vector_type(4))) short short4_t;
typedef __attribute__((ext_vector_type(4))) float f32x4;

__device__ __forceinline__ float sigmoidf_(float x) { return 1.f / (1.f + __expf(-x)); }
__device__ __forceinline__ short bf16s(float f) {
    union { __hip_bfloat16 h; short s; } u; u.h = __float2bfloat16(f); return u.s;
}
#define GLOAD_LDS16(g, l) \
    __builtin_amdgcn_global_load_lds((const __attribute__((address_space(1))) void*)(g), \
                                     (__attribute__((address_space(3))) void*)(l), 16, 0, 0)

// ---------- prep: W3n^T bf16, pre-swizzled so p_kernel can global_load_lds linearly ----------
// Bprep[((p*256 + k)*8 + G)*8 + e] = bf16( W3[(513 + p*64 + (G^(k&7))*8 + e)*256 + k] )
__global__ __launch_bounds__(256) void prep_kernel(const float* __restrict__ W3,
                                                   short* __restrict__ Bprep)
{
    const int idx = blockIdx.x * 256 + threadIdx.x;   // 0..8191
    const int p = idx >> 11;
    const int k = (idx >> 3) & 255;
    const int G = idx & 7;
    const int dbase = p * 64 + ((G ^ (k & 7)) << 3);
    #pragma unroll
    for (int e = 0; e < 8; ++e)
        Bprep[idx * 8 + e] = bf16s(W3[(size_t)(513 + dbase + e) * D + k]);
}

// ---------- emo/cau = relu(text @ rep_W + rep_b) ----------
__global__ __launch_bounds__(256) void rep_kernel(
    const float* __restrict__ te, const float* __restrict__ tc,
    const float* __restrict__ W,  const float* __restrict__ b,
    float* __restrict__ emo, float* __restrict__ cau)
{
    const int row = blockIdx.x;
    const float* x; float* o;
    if (row < SE) { x = te + row * D;        o = emo + row * D; }
    else          { x = tc + (row - SE) * D; o = cau + (row - SE) * D; }
    __shared__ float xs[D];
    const int k = threadIdx.x;
    xs[k] = x[k];
    __syncthreads();
    float acc = b[k];
    #pragma unroll 8
    for (int d = 0; d < D; ++d) acc = fmaf(xs[d], W[d * D + k], acc);
    o[k] = fmaxf(acc, 0.f);
}

// ---------- GRU over each chunk of 8 cau rows ----------
__global__ __launch_bounds__(768) void gru_kernel(
    const float* __restrict__ cau,
    const float* __restrict__ Wih, const float* __restrict__ Whh,
    const float* __restrict__ bih, const float* __restrict__ bhh,
    float* __restrict__ ch_last)
{
    const int c = blockIdx.x;
    const int t = threadIdx.x;
    __shared__ float h[D], x[D], gx[3 * D], gh[3 * D];
    if (t < D) h[t] = 0.f;
    __syncthreads();
    for (int s = 0; s < CKS; ++s) {
        if (t < D) x[t] = cau[(c * CKS + s) * D + t];
        __syncthreads();
        float a = bih[t], g = bhh[t];
        #pragma unroll 4
        for (int d = 0; d < D; ++d) {
            a = fmaf(x[d], Wih[d * 768 + t], a);
            g = fmaf(h[d], Whh[d * 768 + t], g);
        }
        gx[t] = a; gh[t] = g;
        __syncthreads();
        if (t < D) {
            float r = sigmoidf_(gx[t] + gh[t]);
            float z = sigmoidf_(gx[D + t] + gh[D + t]);
            float n = tanhf(gx[2 * D + t] + r * gh[2 * D + t]);
            h[t] = (1.f - z) * n + z * h[t];
        }
        __syncthreads();
    }
    if (t < D) ch_last[c * D + t] = h[t];
}

// ---------- dual linear: O1 = X1 @ W[0:D], O2 = X2 @ W[D:2D] + bias ----------
__global__ __launch_bounds__(256) void dual_lin_kernel(
    const float* __restrict__ X1, int n1,
    const float* __restrict__ X2,
    const float* __restrict__ W,
    const float* __restrict__ bias,
    float* __restrict__ O1, float* __restrict__ O2)
{
    const int row = blockIdx.x;
    const int k = threadIdx.x;
    const float* x; const float* Wp; float* o; float acc;
    if (row < n1) { x = X1 + row * D;        Wp = W;         o = O1 + row * D;        acc = 0.f; }
    else          { x = X2 + (row - n1) * D; Wp = W + D * D; o = O2 + (row - n1) * D; acc = bias[k]; }
    __shared__ float xs[D];
    xs[k] = x[k];
    __syncthreads();
    #pragma unroll 8
    for (int d = 0; d < D; ++d) acc = fmaf(xs[d], Wp[d * D + k], acc);
    o[k] = acc;
}

// ---------- phase2 ----------
__global__ __launch_bounds__(256) void phase2_kernel(
    const float* __restrict__ HE, const float* __restrict__ HC,
    const float* __restrict__ WoW, const float* __restrict__ Wob,
    float* __restrict__ out)
{
    const int i = blockIdx.x, c = blockIdx.y;
    const int k = threadIdx.x;
    const int lane = k & 63, wid = k >> 6;
    float hk = sigmoidf_(HE[i * D + k] + HC[c * D + k]);
    float v0 = hk * WoW[k * 2 + 0];
    float v1 = hk * WoW[k * 2 + 1];
    #pragma unroll
    for (int off = 32; off; off >>= 1) { v0 += __shfl_down(v0, off); v1 += __shfl_down(v1, off); }
    __shared__ float r0[4], r1[4];
    if (lane == 0) { r0[wid] = v0; r1[wid] = v1; }
    __syncthreads();
    if (k == 0) {
        float l0 = r0[0] + r0[1] + r0[2] + r0[3] + Wob[0];
        float l1 = r1[0] + r1[1] + r1[2] + r1[3] + Wob[1];
        float m = fmaxf(l0, l1);
        float lse = m + __logf(__expf(l0 - m) + __expf(l1 - m));
        out[(i * NC + c) * 2 + 0] = l0 - lse;
        out[(i * NC + c) * 2 + 1] = l1 - lse;
    }
}

// ---------- p: MFMA over M-term + fused epilogue ----------
// block = (i, 128-j tile), 512 threads = 8 waves (2j x 4k), per-wave 64j x 64k
__global__ __launch_bounds__(512) void p_kernel(
    const float* __restrict__ emo, const float* __restrict__ cau,
    const float* __restrict__ Ae,  const float* __restrict__ Ac,
    const float* __restrict__ W3,  const short* __restrict__ Bprep,
    const float* __restrict__ clsW, const float* __restrict__ clsb,
    float* __restrict__ pout)
{
    const int t  = threadIdx.x;
    const int i  = blockIdx.x;
    const int j0 = blockIdx.y * 128;
    const int l  = t & 63;
    const int wave = t >> 6;
    const int hi = l >> 4, lo = l & 15;
    const int wj = wave >> 2, wk = wave & 3;
    const int j_base = wj * 64, k_base = wk * 64;

    __shared__ __align__(16) float  e_s[D];
    __shared__ __align__(16) short  A_s[128 * 64];   // [j][d-panel], XOR-swizzled 16B groups
    __shared__ __align__(16) short  B_s[256 * 64];   // [k][d-panel], XOR-swizzled 16B groups
    __shared__ float it2_s[128];
    __shared__ float part2[128][4][2];

    if (t < D) e_s[t] = emo[(size_t)i * D + t];
    __syncthreads();

    f32x4 acc[4][4];
    #pragma unroll
    for (int a = 0; a < 4; ++a)
        #pragma unroll
        for (int b = 0; b < 4; ++b) acc[a][b] = (f32x4)(0.f);

    float dist[4] = {0.f, 0.f, 0.f, 0.f};
    const int jl_base = t >> 4;            // 0..31
    const int dl = (t & 15) * 4;           // 0..60
    const int g_w = dl >> 3, half_w = (dl >> 2) & 1;

    for (int p = 0; p < 4; ++p) {
        // ---- stage A: A[j][d] = bf16(cau[j,d]*emo[i,d]); fold item2 partials ----
        #pragma unroll
        for (int r = 0; r < 4; ++r) {
            const int jl = r * 32 + jl_base;
            const float4 c4 = *(const float4*)&cau[(size_t)(j0 + jl) * D + p * 64 + dl];
            const float4 e4 = *(const float4*)&e_s[p * 64 + dl];
            float dx = e4.x - c4.x, dy = e4.y - c4.y, dz = e4.z - c4.z, dw = e4.w - c4.w;
            dist[r] = fmaf(dx, dx, dist[r]); dist[r] = fmaf(dy, dy, dist[r]);
            dist[r] = fmaf(dz, dz, dist[r]); dist[r] = fmaf(dw, dw, dist[r]);
            short4_t av;
            av.x = bf16s(c4.x * e4.x); av.y = bf16s(c4.y * e4.y);
            av.z = bf16s(c4.z * e4.z); av.w = bf16s(c4.w * e4.w);
            *(short4_t*)&A_s[jl * 64 + ((g_w ^ (jl & 7)) << 3) + half_w * 4] = av;
        }
        // ---- stage B: linear LDS dest, pre-swizzled global source ----
        #pragma unroll
        for (int r = 0; r < 4; ++r) {
            const int flat = r * 512 + t;
            GLOAD_LDS16(Bprep + ((size_t)p * 2048 + flat) * 8, &B_s[flat * 8]);
        }
        __syncthreads();
        // ---- MFMA: 32 per wave per panel ----
        #pragma unroll
        for (int df = 0; df < 2; ++df) {
            const int ge = df * 4 + hi;
            short8_t a[4], b[4];
            #pragma unroll
            for (int jf = 0; jf < 4; ++jf) {
                const int row = j_base + jf * 16 + lo;
                a[jf] = *(const short8_t*)&A_s[row * 64 + ((ge ^ (row & 7)) << 3)];
            }
            #pragma unroll
            for (int kf = 0; kf < 4; ++kf) {
                const int col = k_base + kf * 16 + lo;
                b[kf] = *(const short8_t*)&B_s[col * 64 + ((ge ^ (col & 7)) << 3)];
            }
            #pragma unroll
            for (int jf = 0; jf < 4; ++jf)
                #pragma unroll
                for (int kf = 0; kf < 4; ++kf)
                    acc[jf][kf] = __builtin_amdgcn_mfma_f32_16x16x32_bf16(a[jf], b[kf], acc[jf][kf], 0, 0, 0);
        }
        __syncthreads();
    }

    // ---- item2 reduce (16 lanes x 16 d-chunks each) ----
    #pragma unroll
    for (int r = 0; r < 4; ++r) {
        float v = dist[r];
        v += __shfl_xor(v, 1); v += __shfl_xor(v, 2);
        v += __shfl_xor(v, 4); v += __shfl_xor(v, 8);
        if (lo == 0) it2_s[r * 32 + jl_base] = sqrtf(v);
    }
    __syncthreads();

    // ---- epilogue: s = M + Ae + Ac + it2*wn; relu; cls dot; cross-lane reduce ----
    int   kcol[4]; float Ae_r[4], wn_r[4], c0_r[4], c1_r[4];
    #pragma unroll
    for (int kf = 0; kf < 4; ++kf) {
        const int k = k_base + kf * 16 + lo;
        kcol[kf] = k;
        Ae_r[kf] = Ae[(size_t)i * D + k];
        wn_r[kf] = W3[512 * D + k];
        c0_r[kf] = clsW[k * 2]; c1_r[kf] = clsW[k * 2 + 1];
    }
    #pragma unroll
    for (int jf = 0; jf < 4; ++jf) {
        #pragma unroll
        for (int q = 0; q < 4; ++q) {
            const int j = j_base + jf * 16 + hi * 4 + q;   // C/D layout: row=(l>>4)*4+reg
            const float it2v = it2_s[j];
            const float* AcRow = Ac + (size_t)(j0 + j) * D;
            float sv0 = 0.f, sv1 = 0.f;
            #pragma unroll
            for (int kf = 0; kf < 4; ++kf) {
                float s = acc[jf][kf][q] + Ae_r[kf] + AcRow[kcol[kf]] + it2v * wn_r[kf];
                float h = fmaxf(s, 0.f);
                sv0 = fmaf(h, c0_r[kf], sv0); sv1 = fmaf(h, c1_r[kf], sv1);
            }
            sv0 += __shfl_xor(sv0, 1); sv0 += __shfl_xor(sv0, 2);
            sv0 += __shfl_xor(sv0, 4); sv0 += __shfl_xor(sv0, 8);
            sv1 += __shfl_xor(sv1, 1); sv1 += __shfl_xor(sv1, 2);
            sv1 += __shfl_xor(sv1, 4); sv1 += __shfl_xor(sv1, 8);
            if (lo == 0) { part2[j][wk][0] = sv0; part2[j][wk][1] = sv1; }
        }
    }
    __syncthreads();
    if (t < 128) {
        float s0 = part2[t][0][0] + part2[t][1][0] + part2[t][2][0] + part2[t][3][0] + clsb[0];
        float s1 = part2[t][0][1] + part2[t][1][1] + part2[t][2][1] + part2[t][3][1] + clsb[1];
        float m = fmaxf(s0, s1);
        float lse = m + __logf(__expf(s0 - m) + __expf(s1 - m));
        float2 o; o.x = s0 - lse; o.y = s1 - lse;
        *(float2*)&pout[((size_t)i * SC + j0 + t) * 2] = o;
    }
}

// ---------- L_cau ----------
__global__ void zero_kernel(float* __restrict__ p, int n)
{
    int i = blockIdx.x * blockDim.x + threadIdx.x;
    if (i < n) p[i] = 0.f;
}
__global__ void scatter_kernel(const int* __restrict__ label3, float* __restrict__ Lcau)
{
    int i = blockIdx.x * blockDim.x + threadIdx.x;
    if (i < SE) {
        #pragma unroll
        for (int t = 0; t < KC; ++t) {
            int j = label3[i * KC + t];
            Lcau[i * SC + j] = 1.0f;
        }
    }
}

extern "C" void kernel_launch(void* const* d_in, const int* in_sizes, int n_in,
                              void* d_out, int out_size, void* d_ws, size_t ws_size,
                              hipStream_t stream)
{
    const float* text_emo = (const float*)d_in[0];
    const float* text_cau = (const float*)d_in[1];
    const int*   label3   = (const int*)d_in[3];
    const float* rep_W = (const float*)d_in[5];
    const float* rep_b = (const float*)d_in[6];
    const float* W_W   = (const float*)d_in[7];
    const float* W_b   = (const float*)d_in[8];
    const float* Wo_W  = (const float*)d_in[9];
    const float* Wo_b  = (const float*)d_in[10];
    const float* gWih  = (const float*)d_in[11];
    const float* gWhh  = (const float*)d_in[12];
    const float* gbih  = (const float*)d_in[13];
    const float* gbhh  = (const float*)d_in[14];
    const float* W3_W  = (const float*)d_in[15];
    const float* W3_b  = (const float*)d_in[16];
    const float* cls_W = (const float*)d_in[17];
    const float* cls_b = (const float*)d_in[18];

    float* out        = (float*)d_out;
    float* phase2_out = out;
    float* p_out      = out + SE * NC * 2;
    float* lcau_out   = out + SE * NC * 2 + SE * SC * 2;

    float* ws  = (float*)d_ws;
    float* emo = ws;              // 512*256
    float* cau = emo + SE * D;    // 512*256
    float* chl = cau + SC * D;    // 64*256
    float* HE  = chl + NC * D;    // 512*256
    float* HC  = HE + SE * D;     // 64*256
    float* Ae  = HC + NC * D;     // 512*256
    float* Ac  = Ae + SE * D;     // 512*256
    short* Bprep = (short*)(Ac + SC * D);  // 256*256 bf16 = 128KB

    prep_kernel<<<32, 256, 0, stream>>>(W3_W, Bprep);
    rep_kernel<<<SE + SC, 256, 0, stream>>>(text_emo, text_cau, rep_W, rep_b, emo, cau);
    gru_kernel<<<NC, 768, 0, stream>>>(cau, gWih, gWhh, gbih, gbhh, chl);
    dual_lin_kernel<<<SE + NC, 256, 0, stream>>>(emo, SE, chl, W_W, W_b, HE, HC);
    dual_lin_kernel<<<SE + SC, 256, 0, stream>>>(emo, SE, cau, W3_W, W3_b, Ae, Ac);
    phase2_kernel<<<dim3(SE, NC), 256, 0, stream>>>(HE, HC, Wo_W, Wo_b, phase2_out);
    p_kernel<<<dim3(SE, 4), 512, 0, stream>>>(emo, cau, Ae, Ac, W3_W, Bprep, cls_W, cls_b, p_out);
    zero_kernel<<<(SE * SC + 255) / 256, 256, 0, stream>>>(lcau_out, SE * SC);
    scatter_kernel<<<2, 256, 0, stream>>>(label3, lcau_out);
}

// Round 3
// 215.480 us; speedup vs baseline: 6.1813x; 1.4126x over previous
//
#include <hip/hip_runtime.h>
#include <hip/hip_bf16.h>
#include <hip/hip_fp16.h>
#include <math.h>

#define D   256
#define SE  512
#define SC  512
#define CKS 8
#define NC  64   // SC / CKS
#define KC  3

typedef __attribute__((ext_vector_type(8))) short short8_t;
typedef __attribute__((ext_vector_type(4))) short short4_t;
typedef __attribute__((ext_vector_type(4))) float f32x4;

__device__ __forceinline__ float sigmoidf_(float x) { return 1.f / (1.f + __expf(-x)); }
__device__ __forceinline__ short bf16s(float f) {
    union { __hip_bfloat16 h; short s; } u; u.h = __float2bfloat16(f); return u.s;
}
#define GLOAD_LDS16(g, l) \
    __builtin_amdgcn_global_load_lds((const __attribute__((address_space(1))) void*)(g), \
                                     (__attribute__((address_space(3))) void*)(l), 16, 0, 0)

// ============ prep: all weight conversions in one kernel ============
// blocks [0,32):   Bprep  (W3 rows 513..768 -> bf16, transposed + XOR-preswizzled)
// blocks [32,224): Wih16  (f16 quad-packed, [d4*768+n] uint2)
// blocks [224,416):Whh16  (same)
// blocks [416,544):WWq    (W_W f32 quad-packed [h][d4][k] float4)
// blocks [544,672):W3q    (W3 rows 0..511, same)
__global__ __launch_bounds__(256) void prep_all_kernel(
    const float* __restrict__ W3, const float* __restrict__ Wih,
    const float* __restrict__ Whh, const float* __restrict__ WW,
    short* __restrict__ Bprep, uint2* __restrict__ Wih16, uint2* __restrict__ Whh16,
    float4* __restrict__ WWq, float4* __restrict__ W3q)
{
    const int b = blockIdx.x, t = threadIdx.x;
    if (b < 32) {
        const int idx = b * 256 + t;
        const int p = idx >> 11, k = (idx >> 3) & 255, G = idx & 7;
        const int dbase = p * 64 + ((G ^ (k & 7)) << 3);
        #pragma unroll
        for (int e = 0; e < 8; ++e)
            Bprep[idx * 8 + e] = bf16s(W3[(size_t)(513 + dbase + e) * D + k]);
    } else if (b < 416) {
        const bool ih = (b < 224);
        const int tid = (b - (ih ? 32 : 224)) * 256 + t;   // 0..49151 = d4*768+n
        const float* W = ih ? Wih : Whh;
        const int base = (tid / 768) * 4 * 768 + (tid % 768);
        float f0 = W[base], f1 = W[base + 768], f2 = W[base + 1536], f3 = W[base + 2304];
        __half2 plo = __halves2half2(__float2half_rn(f0), __float2half_rn(f1));
        __half2 phi = __halves2half2(__float2half_rn(f2), __float2half_rn(f3));
        uint2 o; o.x = *(unsigned int*)&plo; o.y = *(unsigned int*)&phi;
        (ih ? Wih16 : Whh16)[tid] = o;
    } else {
        const bool ww = (b < 544);
        const int tid = (b - (ww ? 416 : 544)) * 256 + t;  // 0..32767
        const int h = tid >> 14, rem = tid & 16383, d4 = rem >> 8, k = rem & 255;
        const float* src = (ww ? WW : W3) + (size_t)(h * 256 + 4 * d4) * D + k;
        (ww ? WWq : W3q)[tid] = make_float4(src[0], src[256], src[512], src[768]);
    }
}

// ============ emo/cau = relu(text @ rep_W + rep_b) ============
__global__ __launch_bounds__(256) void rep_kernel(
    const float* __restrict__ te, const float* __restrict__ tc,
    const float* __restrict__ W,  const float* __restrict__ b,
    float* __restrict__ emo, float* __restrict__ cau)
{
    const int row = blockIdx.x;
    const float* x; float* o;
    if (row < SE) { x = te + row * D;        o = emo + row * D; }
    else          { x = tc + (row - SE) * D; o = cau + (row - SE) * D; }
    __shared__ float xs[D];
    const int k = threadIdx.x;
    xs[k] = x[k];
    __syncthreads();
    float acc = b[k];
    #pragma unroll 8
    for (int d = 0; d < D; ++d) acc = fmaf(xs[d], W[d * D + k], acc);
    o[k] = fmaxf(acc, 0.f);
}

// ============ GX = cau @ Wih + bih  (f16 quads, f16 out) ============
__global__ __launch_bounds__(768) void gx_kernel(
    const float* __restrict__ cau, const uint2* __restrict__ Wih16,
    const float* __restrict__ bih, __half* __restrict__ GX16)
{
    const int row = blockIdx.x, t = threadIdx.x;
    __shared__ uint2 xs4[64];
    if (t < 64) {
        float4 v = *(const float4*)&cau[(size_t)row * D + t * 4];
        __half2 plo = __halves2half2(__float2half_rn(v.x), __float2half_rn(v.y));
        __half2 phi = __halves2half2(__float2half_rn(v.z), __float2half_rn(v.w));
        uint2 o; o.x = *(unsigned int*)&plo; o.y = *(unsigned int*)&phi;
        xs4[t] = o;
    }
    __syncthreads();
    __half2 a0 = __float2half2_rn(0.f), a1 = __float2half2_rn(0.f);
    #pragma unroll 8
    for (int q = 0; q < 64; ++q) {
        uint2 w = Wih16[q * 768 + t];
        uint2 xv = xs4[q];
        a0 = __hfma2(*(__half2*)&w.x, *(__half2*)&xv.x, a0);
        a1 = __hfma2(*(__half2*)&w.y, *(__half2*)&xv.y, a1);
    }
    float g = bih[t] + __low2float(a0) + __high2float(a0) + __low2float(a1) + __high2float(a1);
    GX16[(size_t)row * 768 + t] = __float2half_rn(g);
}

// ============ GRU recurrence over each chunk ============
__global__ __launch_bounds__(768) void gru_rec_kernel(
    const __half* __restrict__ GX16, const uint2* __restrict__ Whh16,
    const float* __restrict__ bhh, float* __restrict__ ch_last)
{
    const int c = blockIdx.x, t = threadIdx.x;
    __shared__ uint2 hqu[64];
    __shared__ float gh_s[768];
    float h = 0.f;
    if (t < 64) { uint2 z; z.x = 0u; z.y = 0u; hqu[t] = z; }
    __syncthreads();
    const float bh = bhh[t];
    for (int s = 0; s < CKS; ++s) {
        const int row = c * CKS + s;
        __half2 a0 = __float2half2_rn(0.f), a1 = __float2half2_rn(0.f);
        #pragma unroll 8
        for (int q = 0; q < 64; ++q) {
            uint2 w = Whh16[q * 768 + t];
            uint2 hv = hqu[q];
            a0 = __hfma2(*(__half2*)&w.x, *(__half2*)&hv.x, a0);
            a1 = __hfma2(*(__half2*)&w.y, *(__half2*)&hv.y, a1);
        }
        gh_s[t] = bh + __low2float(a0) + __high2float(a0) + __low2float(a1) + __high2float(a1);
        __syncthreads();
        if (t < 256) {
            const float gxr = __half2float(GX16[(size_t)row * 768 + t]);
            const float gxz = __half2float(GX16[(size_t)row * 768 + 256 + t]);
            const float gxn = __half2float(GX16[(size_t)row * 768 + 512 + t]);
            float r = sigmoidf_(gxr + gh_s[t]);
            float z = sigmoidf_(gxz + gh_s[256 + t]);
            float n = tanhf(gxn + r * gh_s[512 + t]);
            h = (1.f - z) * n + z * h;
            float f1 = __shfl_down(h, 1);
            float f2 = __shfl_down(h, 2);
            float f3 = __shfl_down(h, 3);
            if ((t & 3) == 0) {
                __half2 plo = __halves2half2(__float2half_rn(h),  __float2half_rn(f1));
                __half2 phi = __halves2half2(__float2half_rn(f2), __float2half_rn(f3));
                uint2 o; o.x = *(unsigned int*)&plo; o.y = *(unsigned int*)&phi;
                hqu[t >> 2] = o;
            }
        }
        __syncthreads();
    }
    if (t < 256) ch_last[c * D + t] = h;
}

// ============ merged linears: HE, HC, Ae, Ac(bf16) ============
__global__ __launch_bounds__(256) void dual_all_kernel(
    const float* __restrict__ emo, const float* __restrict__ cau, const float* __restrict__ chl,
    const float4* __restrict__ WWq, const float4* __restrict__ W3q,
    const float* __restrict__ Wb, const float* __restrict__ W3b,
    float* __restrict__ HE, float* __restrict__ HC, float* __restrict__ Ae,
    __hip_bfloat16* __restrict__ AcB)
{
    const int b = blockIdx.x, t = threadIdx.x;
    const float* X; const float4* Wq; float acc;
    float* outF = nullptr; __hip_bfloat16* outB = nullptr;
    if (b < 512)       { X = emo + (size_t)b * D;          Wq = WWq;         acc = 0.f;    outF = HE + (size_t)b * D; }
    else if (b < 576)  { X = chl + (size_t)(b - 512) * D;  Wq = WWq + 16384; acc = Wb[t];  outF = HC + (size_t)(b - 512) * D; }
    else if (b < 1088) { X = emo + (size_t)(b - 576) * D;  Wq = W3q;         acc = 0.f;    outF = Ae + (size_t)(b - 576) * D; }
    else               { X = cau + (size_t)(b - 1088) * D; Wq = W3q + 16384; acc = W3b[t]; outB = AcB + (size_t)(b - 1088) * D; }
    __shared__ __align__(16) float xs[D];
    xs[t] = X[t];
    __syncthreads();
    #pragma unroll 8
    for (int q = 0; q < 64; ++q) {
        float4 w = Wq[q * 256 + t];
        float4 x = *(const float4*)&xs[q * 4];
        acc = fmaf(x.x, w.x, acc); acc = fmaf(x.y, w.y, acc);
        acc = fmaf(x.z, w.z, acc); acc = fmaf(x.w, w.w, acc);
    }
    if (outF) outF[t] = acc; else outB[t] = __float2bfloat16(acc);
}

// ============ phase2: one block per i ============
__global__ __launch_bounds__(256) void phase2_kernel(
    const float* __restrict__ HE, const float* __restrict__ HC,
    const float* __restrict__ WoW, const float* __restrict__ Wob,
    float* __restrict__ out)
{
    const int i = blockIdx.x, t = threadIdx.x;
    const int c = t >> 2, sub = t & 3;
    __shared__ __align__(16) float he_s[D];
    he_s[t] = HE[(size_t)i * D + t];
    __syncthreads();
    float v0 = 0.f, v1 = 0.f;
    const float* hcRow = HC + (size_t)c * D;
    #pragma unroll 4
    for (int kk = 0; kk < 16; ++kk) {
        const int k4 = sub * 64 + kk * 4;
        float4 he = *(const float4*)&he_s[k4];
        float4 hc = *(const float4*)&hcRow[k4];
        float hk;
        hk = sigmoidf_(he.x + hc.x); { float2 wo = *(const float2*)&WoW[(k4 + 0) * 2]; v0 = fmaf(hk, wo.x, v0); v1 = fmaf(hk, wo.y, v1); }
        hk = sigmoidf_(he.y + hc.y); { float2 wo = *(const float2*)&WoW[(k4 + 1) * 2]; v0 = fmaf(hk, wo.x, v0); v1 = fmaf(hk, wo.y, v1); }
        hk = sigmoidf_(he.z + hc.z); { float2 wo = *(const float2*)&WoW[(k4 + 2) * 2]; v0 = fmaf(hk, wo.x, v0); v1 = fmaf(hk, wo.y, v1); }
        hk = sigmoidf_(he.w + hc.w); { float2 wo = *(const float2*)&WoW[(k4 + 3) * 2]; v0 = fmaf(hk, wo.x, v0); v1 = fmaf(hk, wo.y, v1); }
    }
    v0 += __shfl_xor(v0, 1); v0 += __shfl_xor(v0, 2);
    v1 += __shfl_xor(v1, 1); v1 += __shfl_xor(v1, 2);
    if (sub == 0) {
        float l0 = v0 + Wob[0], l1 = v1 + Wob[1];
        float m = fmaxf(l0, l1);
        float lse = m + __logf(__expf(l0 - m) + __expf(l1 - m));
        float2 o; o.x = l0 - lse; o.y = l1 - lse;
        *(float2*)&out[((size_t)i * NC + c) * 2] = o;
    }
}

// ============ p: B-resident MFMA, 8 i per block ============
__global__ __launch_bounds__(512, 1) void p_kernel(
    const float* __restrict__ emo, const float* __restrict__ cau,
    const float* __restrict__ Ae,  const __hip_bfloat16* __restrict__ AcB,
    const float* __restrict__ wn,  const short* __restrict__ Bprep,
    const float* __restrict__ clsW, const float* __restrict__ clsb,
    float* __restrict__ pout)
{
    const int t = threadIdx.x;
    const int i0 = blockIdx.x * 8;
    const int j0 = blockIdx.y * 128;
    const int l = t & 63, wave = t >> 6;
    const int hi = l >> 4, lo = l & 15;
    const int wj = wave >> 2, wk = wave & 3;
    const int j_base = wj * 64, k_base = wk * 64;

    __shared__ __align__(16) short B_s[65536];   // 128 KB, all 4 K-panels
    __shared__ __align__(16) short A_s[8192];    // 16 KB, one K-panel
    __shared__ float it2_s[128];
    __shared__ float part2[128][4][2];

    // stage all of B once
    #pragma unroll
    for (int r = 0; r < 16; ++r) {
        const int G = r * 512 + t;
        GLOAD_LDS16(Bprep + G * 8, &B_s[G * 8]);
    }

    // cau tile -> registers (64 VGPR)
    const int jlb = t >> 4;            // 0..31
    const int dl = (t & 15) * 4;
    float4 cr[4][4];
    #pragma unroll
    for (int p = 0; p < 4; ++p)
        #pragma unroll
        for (int r = 0; r < 4; ++r)
            cr[p][r] = *(const float4*)&cau[(size_t)(j0 + r * 32 + jlb) * D + p * 64 + dl];

    const int g_w = dl >> 3, half_w = (dl >> 2) & 1;
    int addrA[4];
    #pragma unroll
    for (int r = 0; r < 4; ++r)
        addrA[r] = (r * 32 + jlb) * 64 + ((g_w ^ (jlb & 7)) << 3) + half_w * 4;

    int kcol[4]; float wn_r[4], c0_r[4], c1_r[4];
    #pragma unroll
    for (int kf = 0; kf < 4; ++kf) {
        const int k = k_base + kf * 16 + lo;
        kcol[kf] = k;
        wn_r[kf] = wn[k];
        c0_r[kf] = clsW[k * 2]; c1_r[kf] = clsW[k * 2 + 1];
    }
    __syncthreads();   // B resident

    for (int ii = 0; ii < 8; ++ii) {
        const int i = i0 + ii;
        f32x4 acc[4][4];
        #pragma unroll
        for (int a = 0; a < 4; ++a)
            #pragma unroll
            for (int b2 = 0; b2 < 4; ++b2) acc[a][b2] = (f32x4)(0.f);
        float dist[4] = {0.f, 0.f, 0.f, 0.f};

        for (int p = 0; p < 4; ++p) {
            const float4 e4 = *(const float4*)&emo[(size_t)i * D + p * 64 + dl];
            __syncthreads();   // previous MFMA reads of A_s done
            #pragma unroll
            for (int r = 0; r < 4; ++r) {
                const float4 c4 = cr[p][r];
                float dx = e4.x - c4.x, dy = e4.y - c4.y, dz = e4.z - c4.z, dw = e4.w - c4.w;
                dist[r] = fmaf(dx, dx, dist[r]); dist[r] = fmaf(dy, dy, dist[r]);
                dist[r] = fmaf(dz, dz, dist[r]); dist[r] = fmaf(dw, dw, dist[r]);
                short4_t av;
                av.x = bf16s(c4.x * e4.x); av.y = bf16s(c4.y * e4.y);
                av.z = bf16s(c4.z * e4.z); av.w = bf16s(c4.w * e4.w);
                *(short4_t*)&A_s[addrA[r]] = av;
            }
            __syncthreads();   // A panel ready
            #pragma unroll
            for (int df = 0; df < 2; ++df) {
                const int ge = df * 4 + hi;
                short8_t a[4], b[4];
                #pragma unroll
                for (int jf = 0; jf < 4; ++jf) {
                    const int row = j_base + jf * 16 + lo;
                    a[jf] = *(const short8_t*)&A_s[row * 64 + ((ge ^ (row & 7)) << 3)];
                }
                #pragma unroll
                for (int kf = 0; kf < 4; ++kf) {
                    const int col = k_base + kf * 16 + lo;
                    b[kf] = *(const short8_t*)&B_s[p * 16384 + col * 64 + ((ge ^ (col & 7)) << 3)];
                }
                #pragma unroll
                for (int jf = 0; jf < 4; ++jf)
                    #pragma unroll
                    for (int kf = 0; kf < 4; ++kf)
                        acc[jf][kf] = __builtin_amdgcn_mfma_f32_16x16x32_bf16(a[jf], b[kf], acc[jf][kf], 0, 0, 0);
            }
        }

        // it2 = ||emo_i - cau_j||
        #pragma unroll
        for (int r = 0; r < 4; ++r) {
            float v = dist[r];
            v += __shfl_xor(v, 1); v += __shfl_xor(v, 2);
            v += __shfl_xor(v, 4); v += __shfl_xor(v, 8);
            if (lo == 0) it2_s[r * 32 + jlb] = sqrtf(v);
        }
        __syncthreads();

        // epilogue
        float Ae_r[4];
        #pragma unroll
        for (int kf = 0; kf < 4; ++kf) Ae_r[kf] = Ae[(size_t)i * D + kcol[kf]];
        #pragma unroll
        for (int jf = 0; jf < 4; ++jf) {
            #pragma unroll
            for (int q = 0; q < 4; ++q) {
                const int j = j_base + jf * 16 + hi * 4 + q;
                const float it2v = it2_s[j];
                const __hip_bfloat16* AcRow = AcB + (size_t)(j0 + j) * D;
                float sv0 = 0.f, sv1 = 0.f;
                #pragma unroll
                for (int kf = 0; kf < 4; ++kf) {
                    float s = acc[jf][kf][q] + Ae_r[kf] + __bfloat162float(AcRow[kcol[kf]]) + it2v * wn_r[kf];
                    float h = fmaxf(s, 0.f);
                    sv0 = fmaf(h, c0_r[kf], sv0); sv1 = fmaf(h, c1_r[kf], sv1);
                }
                sv0 += __shfl_xor(sv0, 1); sv0 += __shfl_xor(sv0, 2);
                sv0 += __shfl_xor(sv0, 4); sv0 += __shfl_xor(sv0, 8);
                sv1 += __shfl_xor(sv1, 1); sv1 += __shfl_xor(sv1, 2);
                sv1 += __shfl_xor(sv1, 4); sv1 += __shfl_xor(sv1, 8);
                if (lo == 0) { part2[j][wk][0] = sv0; part2[j][wk][1] = sv1; }
            }
        }
        __syncthreads();
        if (t < 128) {
            float s0 = part2[t][0][0] + part2[t][1][0] + part2[t][2][0] + part2[t][3][0] + clsb[0];
            float s1 = part2[t][0][1] + part2[t][1][1] + part2[t][2][1] + part2[t][3][1] + clsb[1];
            float m = fmaxf(s0, s1);
            float lse = m + __logf(__expf(s0 - m) + __expf(s1 - m));
            float2 o; o.x = s0 - lse; o.y = s1 - lse;
            *(float2*)&pout[((size_t)i * SC + j0 + t) * 2] = o;
        }
    }
}

// ============ L_cau: zero + scatter per row ============
__global__ __launch_bounds__(128) void lcau_kernel(const int* __restrict__ label3, float* __restrict__ L)
{
    const int row = blockIdx.x, t = threadIdx.x;
    float4 z; z.x = z.y = z.z = z.w = 0.f;
    *(float4*)&L[(size_t)row * SC + t * 4] = z;
    __syncthreads();
    if (t < KC) {
        int j = label3[row * KC + t];
        L[(size_t)row * SC + j] = 1.0f;
    }
}

extern "C" void kernel_launch(void* const* d_in, const int* in_sizes, int n_in,
                              void* d_out, int out_size, void* d_ws, size_t ws_size,
                              hipStream_t stream)
{
    const float* text_emo = (const float*)d_in[0];
    const float* text_cau = (const float*)d_in[1];
    const int*   label3   = (const int*)d_in[3];
    const float* rep_W = (const float*)d_in[5];
    const float* rep_b = (const float*)d_in[6];
    const float* W_W   = (const float*)d_in[7];
    const float* W_b   = (const float*)d_in[8];
    const float* Wo_W  = (const float*)d_in[9];
    const float* Wo_b  = (const float*)d_in[10];
    const float* gWih  = (const float*)d_in[11];
    const float* gWhh  = (const float*)d_in[12];
    const float* gbih  = (const float*)d_in[13];
    const float* gbhh  = (const float*)d_in[14];
    const float* W3_W  = (const float*)d_in[15];
    const float* W3_b  = (const float*)d_in[16];
    const float* cls_W = (const float*)d_in[17];
    const float* cls_b = (const float*)d_in[18];

    float* out        = (float*)d_out;
    float* phase2_out = out;
    float* p_out      = out + SE * NC * 2;
    float* lcau_out   = out + SE * NC * 2 + SE * SC * 2;

    // workspace layout (5.0 MB total)
    float* ws  = (float*)d_ws;
    float* emo = ws;                    // 131072 f
    float* cau = emo + 131072;          // 131072 f
    float* chl = cau + 131072;          // 16384 f
    float* HE  = chl + 16384;           // 131072 f
    float* HC  = HE + 131072;           // 16384 f
    float* Ae  = HC + 16384;            // 131072 f
    float4* WWq = (float4*)(Ae + 131072);            // 32768 float4
    float4* W3q = WWq + 32768;                       // 32768 float4
    __hip_bfloat16* AcB = (__hip_bfloat16*)(W3q + 32768);  // 131072 bf16
    short* Bprep = (short*)(AcB + 131072);           // 65536 short
    __half* GX16 = (__half*)(Bprep + 65536);         // 393216 half
    uint2* Wih16 = (uint2*)(GX16 + 393216);          // 49152 uint2
    uint2* Whh16 = Wih16 + 49152;                    // 49152 uint2

    prep_all_kernel<<<672, 256, 0, stream>>>(W3_W, gWih, gWhh, W_W,
                                             Bprep, Wih16, Whh16, WWq, W3q);
    rep_kernel<<<SE + SC, 256, 0, stream>>>(text_emo, text_cau, rep_W, rep_b, emo, cau);
    gx_kernel<<<SC, 768, 0, stream>>>(cau, Wih16, gbih, GX16);
    gru_rec_kernel<<<NC, 768, 0, stream>>>(GX16, Whh16, gbhh, chl);
    dual_all_kernel<<<1600, 256, 0, stream>>>(emo, cau, chl, WWq, W3q, W_b, W3_b,
                                              HE, HC, Ae, AcB);
    phase2_kernel<<<SE, 256, 0, stream>>>(HE, HC, Wo_W, Wo_b, phase2_out);
    p_kernel<<<dim3(64, 4), 512, 0, stream>>>(emo, cau, Ae, AcB, W3_W + 512 * D,
                                              Bprep, cls_W, cls_b, p_out);
    lcau_kernel<<<SE, 128, 0, stream>>>(label3, lcau_out);
}